// Round 1
// baseline (2229.371 us; speedup 1.0000x reference)
//
#include <hip/hip_runtime.h>

typedef __bf16 bf16x8 __attribute__((ext_vector_type(8)));
typedef float f32x4 __attribute__((ext_vector_type(4)));
typedef unsigned short u16;
typedef unsigned int u32;

#define WIN_N 49
#define CDIM 384
#define NHEADS 12
#define HDIM 32
#define SCALE 0.17677669529663687f
#define WTOK (WIN_N * CDIM)  // 18816 floats per window

__device__ __forceinline__ u16 f2bf(float f) {
  u32 u = __float_as_uint(f);
  u32 r = (u + 0x7FFFu + ((u >> 16) & 1u)) >> 16;
  return (u16)r;
}

// MFMA fragment load from a row-major bf16 matrix (stride in u16 elems,
// stride % 8 == 0 so each 16B read is aligned). Works for LDS or global
// pointers (addrspace inferred after inlining). Zero for rows >= nrows.
// Verified gfx950 mapping: elem j of lane = M[row][k0 + quad*8 + j].
__device__ __forceinline__ bf16x8 ld_frag(const u16* base, int row, int nrows,
                                          int stride, int k0, int quad) {
  bf16x8 z = {};
  if (row < nrows)
    z = *(const bf16x8*)(base + (size_t)row * stride + k0 + quad * 8);
  return z;
}

// ---------------- prep: weights -> bf16, bias gather, x -> bf16 ----------------
// x bf16 goes into the FIRST 37632 B of each window's own out-region (window-
// disjoint scratch; fully overwritten by the final proj result).
__global__ void prep_kernel(const float* __restrict__ x,
                            const float* __restrict__ qkv_w,
                            const float* __restrict__ proj_w,
                            const float* __restrict__ bias_table,
                            const int* __restrict__ rel_index,
                            u16* __restrict__ qkvWb, u16* __restrict__ projWb,
                            float* __restrict__ biasF, float* __restrict__ out) {
  int i = blockIdx.x * blockDim.x + threadIdx.x;
  int stride = gridDim.x * blockDim.x;
  for (int t = i; t < 3 * CDIM * CDIM; t += stride) qkvWb[t] = f2bf(qkv_w[t]);
  for (int t = i; t < CDIM * CDIM; t += stride) projWb[t] = f2bf(proj_w[t]);
  for (int t = i; t < NHEADS * WIN_N * WIN_N; t += stride) {
    int h = t / (WIN_N * WIN_N);
    int r = t - h * (WIN_N * WIN_N);
    biasF[t] = bias_table[rel_index[r] * NHEADS + h];
  }
  // x: 4096 windows x 4704 float4 each
  const float4* xv = (const float4*)x;
  for (u32 t = (u32)i; t < 4096u * 4704u; t += (u32)stride) {
    u32 b = t / 4704u, r = t - b * 4704u;
    float4 v = xv[t];
    u32* dst = (u32*)((u16*)(out + (size_t)b * WTOK) + r * 4u);
    dst[0] = (u32)f2bf(v.x) | ((u32)f2bf(v.y) << 16);
    dst[1] = (u32)f2bf(v.z) | ((u32)f2bf(v.w) << 16);
  }
}

// ---------------- fused QKV + window attention ----------------
// 1 block = 1 window, 256 threads = 4 waves. Per head-group (2 heads, 6 groups):
//   QKV (MFMA; X from global bf16 scratch, W from global bf16) -> Q,K (LDS) / V (LDS, T)
//   S = Q@K^T -> quad-shuffle softmax -> P (LDS, wave-private rows: no barrier)
//   O = P@V -> written bf16 to global AttnOut scratch (second half of window region)
// Only 2 barriers per group: (a) guards Q/K/V overwrite vs prior-group reads,
// (b) guards Q/K/V write -> read. P is wave-private (each wave writes AND reads
// only its own m-half rows), so the old (c)/(d)/(f) barriers are gone.
// LDS 37,440 B + <=128 VGPR -> 4 blocks/CU (16 waves) vs previous 2 (8 waves).
__global__ void __launch_bounds__(256, 4)
swin_attn(const float* __restrict__ qkv_b, const u16* __restrict__ qkvWb,
          const float* __restrict__ biasF, float* __restrict__ out) {
  // LDS map (u16 elems): Qb@0 49x72 | Kb@3528 49x72 | Vt@7056 64x72 | Pb@11664 2x(49x72)
  __shared__ __align__(16) u16 sm[18720];  // 37,440 B
  u16* Qb = sm;
  u16* Kb = sm + 3528;
  u16* Vt = sm + 7056;
  u16* Pb = sm + 11664;

  const int tid = threadIdx.x;
  const int w = tid >> 6, lane = tid & 63, quad = lane >> 4, l16 = lane & 15;
  const int b = blockIdx.x;
  const int mhalf = w & 1, hh = w >> 1;  // attention: wave -> (head hh, M-half)

  u16* winBase = (u16*)(out + (size_t)b * WTOK);
  const u16* Xg = winBase;         // 49 x 384 bf16 (written by prep)
  u16* Ao = winBase + WTOK;        // 49 x 384 bf16 attention output scratch

  // zero Vt once (token cols 49..71 must stay 0 across all groups)
  for (int i = tid; i < (64 * 72) / 2; i += 256) ((u32*)Vt)[i] = 0u;

  // per-wave QKV col-tile mapping (3 tiles/wave covering Qh0 Qh1 Kh0 Kh1 Vh0 Vh1)
  int mat[3], hhc[3], half[3];
#pragma unroll
  for (int tl = 0; tl < 3; ++tl) {
    int t = w * 3 + tl;
    int chunk = t >> 1;      // 0..5
    half[tl] = t & 1;        // which 16-col half of the 32
    mat[tl] = chunk >> 1;    // 0=Q 1=K 2=V
    hhc[tl] = chunk & 1;     // head within group
  }

  for (int g = 0; g < 6; ++g) {
    __syncthreads();  // (a) prior group done reading Qb/Kb/Vt/Pb

    // ---- QKV: each wave 3 col-tiles x 4 M-tiles, K = 384 = 12 x 32 ----
    int orow[3];
#pragma unroll
    for (int tl = 0; tl < 3; ++tl)
      orow[tl] = mat[tl] * CDIM + (g * 2 + hhc[tl]) * HDIM + half[tl] * 16 + l16;

    f32x4 acc[3][4];
#pragma unroll
    for (int tl = 0; tl < 3; ++tl)
#pragma unroll
      for (int mt = 0; mt < 4; ++mt) acc[tl][mt] = (f32x4){0.f, 0.f, 0.f, 0.f};

    for (int k = 0; k < 12; ++k) {
      bf16x8 a[4];
#pragma unroll
      for (int mt = 0; mt < 4; ++mt)
        a[mt] = ld_frag(Xg, mt * 16 + l16, WIN_N, CDIM, k * 32, quad);
#pragma unroll
      for (int tl = 0; tl < 3; ++tl) {
        bf16x8 bw = *(const bf16x8*)(qkvWb + (size_t)orow[tl] * CDIM + k * 32 + quad * 8);
#pragma unroll
        for (int mt = 0; mt < 4; ++mt)
          acc[tl][mt] = __builtin_amdgcn_mfma_f32_16x16x32_bf16(a[mt], bw, acc[tl][mt], 0, 0, 0);
      }
    }
#pragma unroll
    for (int tl = 0; tl < 3; ++tl) {
      float bias = qkv_b[orow[tl]];
      int col = hhc[tl] * HDIM + half[tl] * 16 + l16;
#pragma unroll
      for (int mt = 0; mt < 4; ++mt)
#pragma unroll
        for (int r = 0; r < 4; ++r) {
          int tok = mt * 16 + quad * 4 + r;  // C/D row = quad*4 + reg
          if (tok < WIN_N) {
            u16 hv = f2bf(acc[tl][mt][r] + bias);
            if (mat[tl] == 0)      Qb[tok * 72 + col] = hv;
            else if (mat[tl] == 1) Kb[tok * 72 + col] = hv;
            else                   Vt[col * 72 + tok] = hv;  // transposed
          }
        }
    }
    __syncthreads();  // (b) Q,K,V ready

    // ---- S = Q @ K^T (per wave: head hh, M-tiles {2*mhalf, 2*mhalf+1}) ----
    f32x4 S[2][4];
    bf16x8 aq[2];
#pragma unroll
    for (int mt2 = 0; mt2 < 2; ++mt2)
      aq[mt2] = ld_frag(Qb, (2 * mhalf + mt2) * 16 + l16, WIN_N, 72, hh * HDIM, quad);
#pragma unroll
    for (int nt = 0; nt < 4; ++nt) {
      bf16x8 bk = ld_frag(Kb, nt * 16 + l16, WIN_N, 72, hh * HDIM, quad);
#pragma unroll
      for (int mt2 = 0; mt2 < 2; ++mt2) {
        f32x4 z = (f32x4){0.f, 0.f, 0.f, 0.f};
        S[mt2][nt] = __builtin_amdgcn_mfma_f32_16x16x32_bf16(aq[mt2], bk, z, 0, 0, 0);
      }
    }
    // ---- softmax over rows (row lives in one 16-lane quad group) ----
    const int hglob = g * 2 + hh;
#pragma unroll
    for (int mt2 = 0; mt2 < 2; ++mt2)
#pragma unroll
      for (int r = 0; r < 4; ++r) {
        int m = (2 * mhalf + mt2) * 16 + quad * 4 + r;
        float v[4];
#pragma unroll
        for (int nt = 0; nt < 4; ++nt) {
          int n = nt * 16 + l16;
          float s;
          if (m < WIN_N && n < WIN_N)
            s = S[mt2][nt][r] * SCALE + biasF[(hglob * WIN_N + m) * WIN_N + n];
          else
            s = (m >= WIN_N) ? 0.f : -1e30f;  // pad rows: benign; pad cols: -inf
          v[nt] = s;
        }
        float mx = fmaxf(fmaxf(v[0], v[1]), fmaxf(v[2], v[3]));
        mx = fmaxf(mx, __shfl_xor(mx, 1));
        mx = fmaxf(mx, __shfl_xor(mx, 2));
        mx = fmaxf(mx, __shfl_xor(mx, 4));
        mx = fmaxf(mx, __shfl_xor(mx, 8));
        float sum = 0.f;
#pragma unroll
        for (int nt = 0; nt < 4; ++nt) {
          v[nt] = __expf(v[nt] - mx);
          sum += v[nt];
        }
        sum += __shfl_xor(sum, 1);
        sum += __shfl_xor(sum, 2);
        sum += __shfl_xor(sum, 4);
        sum += __shfl_xor(sum, 8);
        float inv = 1.f / sum;
#pragma unroll
        for (int nt = 0; nt < 4; ++nt) S[mt2][nt][r] = v[nt] * inv;
      }

    // ---- write P (bf16). Rows are WAVE-PRIVATE (own m-half only), and the
    // same wave reads them back below -> same-wave LDS RAW, no barrier. ----
    u16* Ph = Pb + hh * 3528;
#pragma unroll
    for (int mt2 = 0; mt2 < 2; ++mt2)
#pragma unroll
      for (int nt = 0; nt < 4; ++nt)
#pragma unroll
        for (int r = 0; r < 4; ++r) {
          int m = (2 * mhalf + mt2) * 16 + quad * 4 + r;
          if (m < WIN_N) Ph[m * 72 + nt * 16 + l16] = f2bf(S[mt2][nt][r]);
        }

    // ---- O = P @ V ----
    f32x4 o2[2][2];
#pragma unroll
    for (int mt2 = 0; mt2 < 2; ++mt2)
#pragma unroll
      for (int nt2 = 0; nt2 < 2; ++nt2) o2[mt2][nt2] = (f32x4){0.f, 0.f, 0.f, 0.f};
    bf16x8 bv[2][2];
#pragma unroll
    for (int nt2 = 0; nt2 < 2; ++nt2)
#pragma unroll
      for (int kk = 0; kk < 2; ++kk)
        bv[nt2][kk] = ld_frag(Vt, hh * HDIM + nt2 * 16 + l16, 64, 72, kk * 32, quad);
#pragma unroll
    for (int mt2 = 0; mt2 < 2; ++mt2)
#pragma unroll
      for (int kk = 0; kk < 2; ++kk) {
        bf16x8 ap = ld_frag(Ph, (2 * mhalf + mt2) * 16 + l16, WIN_N, 72, kk * 32, quad);
#pragma unroll
        for (int nt2 = 0; nt2 < 2; ++nt2)
          o2[mt2][nt2] = __builtin_amdgcn_mfma_f32_16x16x32_bf16(ap, bv[nt2][kk], o2[mt2][nt2], 0, 0, 0);
      }
    // ---- write AttnOut bf16 to global scratch (16 consecutive u16 per quad) ----
#pragma unroll
    for (int mt2 = 0; mt2 < 2; ++mt2)
#pragma unroll
      for (int nt2 = 0; nt2 < 2; ++nt2)
#pragma unroll
        for (int r = 0; r < 4; ++r) {
          int tok = (2 * mhalf + mt2) * 16 + quad * 4 + r;
          if (tok < WIN_N)
            Ao[tok * CDIM + hglob * HDIM + nt2 * 16 + l16] = f2bf(o2[mt2][nt2][r]);
        }
  }
}

// ---------------- proj GEMM: out = AttnOut @ projW^T + proj_b ----------------
// 1 block = 1 window, 512 threads = 8 waves, 48 out-cols/wave. No LDS;
// pacc[3][4] = 48 regs -> <=128 VGPR -> 2 blocks/CU = 16 waves.
// K-accumulation order k=0..11 matches the old fused per-group order exactly
// (bit-identical results). Reads AttnOut bf16 from the window's own out region,
// then (after a barrier so all waves' reads are done) overwrites it with fp32.
__global__ void __launch_bounds__(512, 4)
swin_proj(const float* __restrict__ proj_b, const u16* __restrict__ projWb,
          float* __restrict__ out) {
  const int tid = threadIdx.x;
  const int w = tid >> 6, lane = tid & 63, quad = lane >> 4, l16 = lane & 15;
  const int b = blockIdx.x;
  const u16* Ain = (const u16*)(out + (size_t)b * WTOK) + WTOK;

  f32x4 pacc[3][4];
#pragma unroll
  for (int t3 = 0; t3 < 3; ++t3)
#pragma unroll
    for (int mt = 0; mt < 4; ++mt) pacc[t3][mt] = (f32x4){0.f, 0.f, 0.f, 0.f};

  for (int k = 0; k < 12; ++k) {
    bf16x8 a[4];
#pragma unroll
    for (int mt = 0; mt < 4; ++mt)
      a[mt] = ld_frag(Ain, mt * 16 + l16, WIN_N, CDIM, k * 32, quad);
#pragma unroll
    for (int t3 = 0; t3 < 3; ++t3) {
      int nrow = w * 48 + t3 * 16 + l16;
      bf16x8 bw = *(const bf16x8*)(projWb + (size_t)nrow * CDIM + k * 32 + quad * 8);
#pragma unroll
      for (int mt = 0; mt < 4; ++mt)
        pacc[t3][mt] = __builtin_amdgcn_mfma_f32_16x16x32_bf16(a[mt], bw, pacc[t3][mt], 0, 0, 0);
    }
  }
  __syncthreads();  // all waves done reading Ain before we overwrite the region

  float* outp = out + (size_t)b * WTOK;
#pragma unroll
  for (int t3 = 0; t3 < 3; ++t3) {
    int n = w * 48 + t3 * 16 + l16;
    float pb = proj_b[n];
#pragma unroll
    for (int mt = 0; mt < 4; ++mt)
#pragma unroll
      for (int r = 0; r < 4; ++r) {
        int m = mt * 16 + quad * 4 + r;
        if (m < WIN_N) outp[m * CDIM + n] = pacc[t3][mt][r] + pb;
      }
  }
}

extern "C" void kernel_launch(void* const* d_in, const int* in_sizes, int n_in,
                              void* d_out, int out_size, void* d_ws, size_t ws_size,
                              hipStream_t stream) {
  const float* x          = (const float*)d_in[0];
  const float* qkv_w      = (const float*)d_in[1];
  const float* qkv_b      = (const float*)d_in[2];
  const float* proj_w     = (const float*)d_in[3];
  const float* proj_b     = (const float*)d_in[4];
  const float* bias_table = (const float*)d_in[5];
  const int*   rel_index  = (const int*)d_in[6];

  // ws layout: qkv_w bf16 (884,736 B) | proj_w bf16 (294,912 B) | biasF fp32 (115,248 B)
  u16* qkvWb = (u16*)d_ws;
  u16* projWb = qkvWb + 3 * CDIM * CDIM;
  float* biasF = (float*)(projWb + CDIM * CDIM);

  hipLaunchKernelGGL(prep_kernel, dim3(2048), dim3(256), 0, stream,
                     x, qkv_w, proj_w, bias_table, rel_index, qkvWb, projWb, biasF,
                     (float*)d_out);
  hipLaunchKernelGGL(swin_attn, dim3(4096), dim3(256), 0, stream,
                     qkv_b, qkvWb, biasF, (float*)d_out);
  hipLaunchKernelGGL(swin_proj, dim3(4096), dim3(512), 0, stream,
                     proj_b, projWb, (float*)d_out);
}